// Round 23
// baseline (84.609 us; speedup 1.0000x reference)
//
#include <hip/hip_runtime.h>
#include <hip/hip_bf16.h>

typedef __bf16 bf16x8 __attribute__((ext_vector_type(8)));
typedef float f32x4 __attribute__((ext_vector_type(4)));
typedef float f32x16 __attribute__((ext_vector_type(16)));

__device__ inline unsigned short f2bf(float f) {
    __hip_bfloat16 h = __float2bfloat16(f);
    return __builtin_bit_cast(unsigned short, h);
}
// packed RNE f32->bf16 convert (HW op, single instruction): dst = {bf16(a), bf16(b)}
__device__ inline unsigned cvtpk(float a, float b) {
    unsigned r;
    asm("v_cvt_pk_bf16_f32 %0, %1, %2" : "=v"(r) : "v"(a), "v"(b));
    return r;
}
// truncation-pack: dst = {hi16(lo), hi16(hi)} via single v_perm_b32 (round-20 win).
__device__ inline unsigned pkhi(float lo, float hi) {
    return __builtin_amdgcn_perm(__builtin_bit_cast(unsigned, hi),
                                 __builtin_bit_cast(unsigned, lo), 0x07060302u);
}
__device__ inline float exp2_fast(float x) {
    float r;
    asm("v_exp_f32 %0, %1" : "=v"(r) : "v"(x));
    return r;
}

#define QSCALE 0.1803368801111244f  /* 0.125 * log2(e) */

// ------- prep: one bandwidth-bound pass producing all bf16 operands ------------------
// x = 4*2048*512 = 4,194,304 f32 -> 2048 blocks x 256 thr x 8 elems (round-22 fix:
// was 4096 blocks = 2x overrun -> device fault).
// blk 0..2047:    xb  = bf16(x)
// blk 2048..2175: wqb = bf16(Wq * QSCALE)  (scale folded pre-rounding)
// blk 2176..2303: wkb = bf16(Wk)
// blk 2304..2559: Vt[b*8+h][d][n'] transpose slice (n' = bit2<->bit3 within 16-block)
__global__ __launch_bounds__(256) void prep(const float* __restrict__ x,
                                            const float* __restrict__ Wq,
                                            const float* __restrict__ Wk,
                                            unsigned short* __restrict__ xb,
                                            unsigned short* __restrict__ wqb,
                                            unsigned short* __restrict__ wkb,
                                            unsigned short* __restrict__ Vt) {
    const int blk = blockIdx.x;
    const int tid = threadIdx.x;
    if (blk < 2048) {
        const size_t i = ((size_t)blk * 256 + tid) * 8;
        float4 v0 = *reinterpret_cast<const float4*>(x + i);
        float4 v1 = *reinterpret_cast<const float4*>(x + i + 4);
        uint4 o = {cvtpk(v0.x, v0.y), cvtpk(v0.z, v0.w), cvtpk(v1.x, v1.y), cvtpk(v1.z, v1.w)};
        *reinterpret_cast<uint4*>(xb + i) = o;
    } else if (blk < 2176) {
        const size_t i = ((size_t)(blk - 2048) * 256 + tid) * 8;
        float4 v0 = *reinterpret_cast<const float4*>(Wq + i);
        float4 v1 = *reinterpret_cast<const float4*>(Wq + i + 4);
        uint4 o = {cvtpk(v0.x * QSCALE, v0.y * QSCALE), cvtpk(v0.z * QSCALE, v0.w * QSCALE),
                   cvtpk(v1.x * QSCALE, v1.y * QSCALE), cvtpk(v1.z * QSCALE, v1.w * QSCALE)};
        *reinterpret_cast<uint4*>(wqb + i) = o;
    } else if (blk < 2304) {
        const size_t i = ((size_t)(blk - 2176) * 256 + tid) * 8;
        float4 v0 = *reinterpret_cast<const float4*>(Wk + i);
        float4 v1 = *reinterpret_cast<const float4*>(Wk + i + 4);
        uint4 o = {cvtpk(v0.x, v0.y), cvtpk(v0.z, v0.w), cvtpk(v1.x, v1.y), cvtpk(v1.z, v1.w)};
        *reinterpret_cast<uint4*>(wkb + i) = o;
    } else {
        const int idx = blk - 2304;          // 0..255 -> (bx 0..7, h 0..7, b 0..3)
        const int lane = tid & 63, w = tid >> 6;
        const int bx = idx & 7, h = (idx >> 3) & 7, b = idx >> 6;
        const int n = bx * 256 + w * 64 + lane;
        const int np = (n & ~15) | (n & 3) | ((n & 4) << 1) | ((n & 8) >> 1);
        const size_t xrow = ((size_t)b * 2048 + n) * 512 + h * 64;
        const size_t vbase = ((size_t)(b * 8 + h) * 64) * 2048 + np;
#pragma unroll
        for (int d0 = 0; d0 < 64; d0 += 4) {
            float4 v = *reinterpret_cast<const float4*>(&x[xrow + d0]);
            Vt[vbase + (size_t)(d0 + 0) * 2048] = f2bf(v.x);
            Vt[vbase + (size_t)(d0 + 1) * 2048] = f2bf(v.y);
            Vt[vbase + (size_t)(d0 + 2) * 2048] = f2bf(v.z);
            Vt[vbase + (size_t)(d0 + 3) * 2048] = f2bf(v.w);
        }
    }
}

// ------- Q/K projection, pure-bf16 pipeline: grid (64, 8) x 256 threads --------------
// by 0..3: Q = xb wqb^T (QSCALE pre-folded into wqb); by 4..7: K = xb wkb^T.
// Staging: 2x16B bf16 loads per matrix per thread per k-iter, direct LDS write, no cvt.
__global__ __launch_bounds__(256) void gemm_qk(const unsigned short* __restrict__ xb,
                                               const unsigned short* __restrict__ wqb,
                                               const unsigned short* __restrict__ wkb,
                                               unsigned short* __restrict__ Qb,
                                               unsigned short* __restrict__ Kb) {
    __shared__ __align__(16) unsigned short sA[128 * 40];
    __shared__ __align__(16) unsigned short sB[128 * 40];
    const int tid  = threadIdx.x;
    const int by   = blockIdx.y;
    const int lane = tid & 63;
    const int wave = tid >> 6;
    const int wr = wave >> 1, wc = wave & 1;
    const int bm = blockIdx.x * 128;
    const unsigned short* __restrict__ Bsrc = (by < 4) ? wqb : wkb;
    unsigned short* __restrict__ C = (by < 4) ? Qb : Kb;
    const int bn = (by & 3) * 128;
    const int tr = tid >> 1, th = (tid & 1) * 16;
    const int rl = lane & 15;
    const int kq = (lane >> 4) * 8;

    f32x4 acc[4][4];
#pragma unroll
    for (int m = 0; m < 4; ++m)
#pragma unroll
        for (int n = 0; n < 4; ++n) acc[m][n] = (f32x4){0.f, 0.f, 0.f, 0.f};

    for (int k0 = 0; k0 < 512; k0 += 32) {
        const unsigned short* ap = &xb[(size_t)(bm + tr) * 512 + k0 + th];
        const unsigned short* bp = &Bsrc[(size_t)(bn + tr) * 512 + k0 + th];
        uint4 a0 = *reinterpret_cast<const uint4*>(ap);
        uint4 a1 = *reinterpret_cast<const uint4*>(ap + 8);
        uint4 b0 = *reinterpret_cast<const uint4*>(bp);
        uint4 b1 = *reinterpret_cast<const uint4*>(bp + 8);
        __syncthreads();
        *reinterpret_cast<uint4*>(&sA[tr * 40 + th])     = a0;
        *reinterpret_cast<uint4*>(&sA[tr * 40 + th + 8]) = a1;
        *reinterpret_cast<uint4*>(&sB[tr * 40 + th])     = b0;
        *reinterpret_cast<uint4*>(&sB[tr * 40 + th + 8]) = b1;
        __syncthreads();

        bf16x8 af[4], bfv[4];
#pragma unroll
        for (int m = 0; m < 4; ++m)
            af[m] = __builtin_bit_cast(bf16x8,
                *reinterpret_cast<const uint4*>(&sA[(wr * 64 + m * 16 + rl) * 40 + kq]));
#pragma unroll
        for (int n = 0; n < 4; ++n)
            bfv[n] = __builtin_bit_cast(bf16x8,
                *reinterpret_cast<const uint4*>(&sB[(wc * 64 + n * 16 + rl) * 40 + kq]));
#pragma unroll
        for (int m = 0; m < 4; ++m)
#pragma unroll
            for (int n = 0; n < 4; ++n)
                acc[m][n] = __builtin_amdgcn_mfma_f32_16x16x32_bf16(af[m], bfv[n], acc[m][n], 0, 0, 0);
    }

    const int rq = (lane >> 4) * 4;
#pragma unroll
    for (int m = 0; m < 4; ++m) {
        int r = bm + wr * 64 + m * 16 + rq;
#pragma unroll
        for (int n = 0; n < 4; ++n) {
            int c = bn + wc * 64 + n * 16 + rl;
#pragma unroll
            for (int reg = 0; reg < 4; ++reg)
                C[(size_t)(r + reg) * 512 + c] = f2bf(acc[m][n][reg]);
        }
    }
}

// ---------------- fused flash attention: 8 waves (4qh x 2jp), dbuf, 1 barrier/tile ---
// (byte-identical to round-21 best: 53 us verified)
__global__ __launch_bounds__(512, 4) void attn_fwd(const unsigned short* __restrict__ Q,
                                                   const unsigned short* __restrict__ Kb,
                                                   const unsigned short* __restrict__ Vt,
                                                   const float* __restrict__ pos,
                                                   float* __restrict__ Out) {
    __shared__ __align__(16) unsigned char smem[42240];
    char* k0b = (char*)smem;                 // 8 KiB
    char* v0b = (char*)smem + 8192;          // 8 KiB
    char* k1b = (char*)smem + 16384;         // 8 KiB
    char* v1b = (char*)smem + 24576;         // 8 KiB
    float* sPosT = (float*)(smem + 32768);   // 2048 f32 slopeL*pos (8 KiB)
    float* sMl   = (float*)(smem + 40960);   // 256 f32 (epilogue l merge)

    const int tid  = threadIdx.x;
    const int lane = tid & 63;
    const int w    = tid >> 6;
    const int l31  = lane & 31;
    const int hi   = lane >> 5;
    const int qh   = w & 3;
    const int jp   = w >> 2;
    // XCD-affine decode (512 blocks, bijective: 512 % 8 == 0)
    const int flat = blockIdx.x;
    const int xcd  = flat & 7;
    const int idx  = flat >> 3;              // 0..63
    const int bh   = xcd * 4 + (idx >> 4);
    const int qt   = idx & 15;
    const int b = bh >> 3, h = bh & 7;
    const int q0 = qt * 128 + qh * 32;
    const size_t rowbase = (size_t)b * 2048;
    const int hc = h * 64;
    const float slopeL = ldexpf(1.4426950408889634f, -(h + 1));  // slope * log2(e)

    // Q B-fragments: lane supplies Q[q=l31][c = ks*16 + hi*8 + e] (Q pre-scaled)
    bf16x8 qf0, qf1, qf2, qf3;
    {
        const unsigned short* qp = &Q[(rowbase + q0 + l31) * 512 + hc + hi * 8];
        qf0 = __builtin_bit_cast(bf16x8, *reinterpret_cast<const uint4*>(qp));
        qf1 = __builtin_bit_cast(bf16x8, *reinterpret_cast<const uint4*>(qp + 16));
        qf2 = __builtin_bit_cast(bf16x8, *reinterpret_cast<const uint4*>(qp + 32));
        qf3 = __builtin_bit_cast(bf16x8, *reinterpret_cast<const uint4*>(qp + 48));
    }
    const float ui = slopeL * pos[rowbase + q0 + l31];

    // one-time slopeL*pos table (512 threads x 4 = 2048)
    {
        float4 v = reinterpret_cast<const float4*>(pos + rowbase)[tid];
        reinterpret_cast<f32x4*>(sPosT)[tid] =
            (f32x4){v.x * slopeL, v.y * slopeL, v.z * slopeL, v.w * slopeL};
    }

    float lloc = 0.f;
    f32x16 o0, o1;
#pragma unroll
    for (int r = 0; r < 16; ++r) { o0[r] = 0.f; o1[r] = 0.f; }

    // staging: 8 threads/row x 16 B; write slot XOR-swizzled -> conflict-free
    const int sr  = tid >> 3;                       // row 0..63
    const int sce = (tid & 7) * 8;                  // elem col (8 elems/thread)
    const int wbyte = sr * 128 + (((tid & 7) * 16) ^ ((sr & 7) << 4));
    const int kswz = (l31 & 7) << 4;                // compute-side swizzle key

    uint4 ck, cv;

    auto stage = [&](int j0v) {
        ck = *reinterpret_cast<const uint4*>(&Kb[(rowbase + j0v + sr) * 512 + hc + sce]);
        cv = *reinterpret_cast<const uint4*>(&Vt[((size_t)bh * 64 + sr) * 2048 + j0v + sce]);
    };
    auto writeb = [&](char* KB, char* VB) {
        *reinterpret_cast<uint4*>(KB + wbyte) = ck;
        *reinterpret_cast<uint4*>(VB + wbyte) = cv;
    };
    auto compute = [&](const char* KB, const char* VB, int j0) {
        const char* kr = KB + (32 * jp + l31) * 128;
        // ---- S chunk (32j x 32q) for this wave's (qh, jp) ----
        f32x16 s;
#pragma unroll
        for (int r = 0; r < 16; ++r) s[r] = 0.f;
        __builtin_amdgcn_s_setprio(1);
#pragma unroll
        for (int ks = 0; ks < 4; ++ks) {
            bf16x8 kf = __builtin_bit_cast(bf16x8,
                *reinterpret_cast<const uint4*>(kr + ((ks * 32 + hi * 16) ^ kswz)));
            bf16x8 qq = (ks == 0) ? qf0 : (ks == 1) ? qf1 : (ks == 2) ? qf2 : qf3;
            s = __builtin_amdgcn_mfma_f32_32x32x16_bf16(kf, qq, s, 0, 0, 0);
        }
        __builtin_amdgcn_s_setprio(0);

        // ---- bias + exp2 (fixed reference, log2 domain) ----
        float ls = 0.f;
#pragma unroll
        for (int t = 0; t < 4; ++t) {
            f32x4 u = *reinterpret_cast<const f32x4*>(&sPosT[j0 + 32 * jp + 8 * t + 4 * hi]);
#pragma unroll
            for (int r = 0; r < 4; ++r) {
                float p = exp2_fast(s[4 * t + r] - fabsf(u[r] - ui));
                s[4 * t + r] = p;
                ls += p;
            }
        }
        lloc += ls;

        // ---- lane-local P fragments (j = 16ks + 4hi + (e&3) + 8*(e>>2)) ----
        bf16x8 pf0 = __builtin_bit_cast(bf16x8, (uint4){
            pkhi(s[0], s[1]),  pkhi(s[2], s[3]),   pkhi(s[4], s[5]),   pkhi(s[6], s[7])});
        bf16x8 pf1 = __builtin_bit_cast(bf16x8, (uint4){
            pkhi(s[8], s[9]),  pkhi(s[10], s[11]), pkhi(s[12], s[13]), pkhi(s[14], s[15])});

        // ---- PV: O^T[d][q] += V-frag x P-frag; V pre-permuted -> single b128/frag ----
        const char* vr0 = VB + l31 * 128;
        const char* vr1 = VB + (32 + l31) * 128;
        __builtin_amdgcn_s_setprio(1);
#pragma unroll
        for (int ks = 0; ks < 2; ++ks) {
            const int cb = (64 * jp + ks * 32 + hi * 16) ^ kswz;  // permuted-stored
            bf16x8 v0 = __builtin_bit_cast(bf16x8, *reinterpret_cast<const uint4*>(vr0 + cb));
            bf16x8 v1 = __builtin_bit_cast(bf16x8, *reinterpret_cast<const uint4*>(vr1 + cb));
            bf16x8 pf = ks ? pf1 : pf0;
            o0 = __builtin_amdgcn_mfma_f32_32x32x16_bf16(v0, pf, o0, 0, 0, 0);
            o1 = __builtin_amdgcn_mfma_f32_32x32x16_bf16(v1, pf, o1, 0, 0, 0);
        }
        __builtin_amdgcn_s_setprio(0);
    };

    // prologue: tile 0 -> buf0; tile 1 -> regs
    stage(0);
    writeb(k0b, v0b);
    stage(64);
    __syncthreads();

    for (int t = 0; t < 32; t += 2) {
        // even iter: compute buf0, regs hold tile t+1 -> buf1
        writeb(k1b, v1b);
        if (t + 2 < 32) stage((t + 2) * 64);
        compute(k0b, v0b, t * 64);
        __syncthreads();
        // odd iter: compute buf1, regs hold tile t+2 -> buf0
        if (t + 2 < 32) {
            writeb(k0b, v0b);
            if (t + 3 < 32) stage((t + 3) * 64);
        }
        compute(k1b, v1b, (t + 1) * 64);
        __syncthreads();
    }

    // ---- epilogue: merge jp partials via LDS, normalize, direct 16B stores ----
    float lt = lloc + __shfl_xor(lloc, 32, 64);  // combine hi halves (same q)
    float* sM = (float*)smem;                    // aliases KV buffers (loop done)
    const int key = (lane & 7) << 2;
    if (jp == 1) {
        float* dst = sM + qh * 2048 + lane * 32;
#pragma unroll
        for (int i = 0; i < 4; ++i) {
            f32x4 t0 = {o0[4 * i], o0[4 * i + 1], o0[4 * i + 2], o0[4 * i + 3]};
            f32x4 t1 = {o1[4 * i], o1[4 * i + 1], o1[4 * i + 2], o1[4 * i + 3]};
            *reinterpret_cast<f32x4*>(dst + ((4 * i) ^ key))      = t0;
            *reinterpret_cast<f32x4*>(dst + ((16 + 4 * i) ^ key)) = t1;
        }
        sMl[qh * 64 + lane] = lt;
    }
    __syncthreads();
    if (jp == 0) {
        const float* src = sM + qh * 2048 + lane * 32;
#pragma unroll
        for (int i = 0; i < 4; ++i) {
            f32x4 t0 = *reinterpret_cast<const f32x4*>(src + ((4 * i) ^ key));
            f32x4 t1 = *reinterpret_cast<const f32x4*>(src + ((16 + 4 * i) ^ key));
#pragma unroll
            for (int r = 0; r < 4; ++r) { o0[4 * i + r] += t0[r]; o1[4 * i + r] += t1[r]; }
        }
        const float linv = 1.0f / (lt + sMl[qh * 64 + lane]);
        float* orow = &Out[(rowbase + q0 + l31) * 512 + hc];
#pragma unroll
        for (int t = 0; t < 4; ++t) {
            f32x4 a, c;
#pragma unroll
            for (int r = 0; r < 4; ++r) {
                a[r] = o0[4 * t + r] * linv;
                c[r] = o1[4 * t + r] * linv;
            }
            *reinterpret_cast<f32x4*>(orow + 8 * t + 4 * hi)      = a;
            *reinterpret_cast<f32x4*>(orow + 32 + 8 * t + 4 * hi) = c;
        }
    }
}

extern "C" void kernel_launch(void* const* d_in, const int* in_sizes, int n_in,
                              void* d_out, int out_size, void* d_ws, size_t ws_size,
                              hipStream_t stream) {
    const float* x   = (const float*)d_in[0];
    const float* pos = (const float*)d_in[1];
    const float* Wq  = (const float*)d_in[2];
    const float* Wk  = (const float*)d_in[3];
    float* out = (float*)d_out;

    // ws (bf16 elems): xb 4.19M | wqb 262K | wkb 262K | Q 4.19M | K 4.19M | Vt 4.19M (~35MB)
    unsigned short* xb  = (unsigned short*)d_ws;
    unsigned short* wqb = xb  + 4194304;
    unsigned short* wkb = wqb + 262144;
    unsigned short* Qb  = wkb + 262144;
    unsigned short* Kbf = Qb  + 4194304;
    unsigned short* Vtb = Kbf + 4194304;

    prep<<<dim3(2560), dim3(256), 0, stream>>>(x, Wq, Wk, xb, wqb, wkb, Vtb);
    gemm_qk<<<dim3(64, 8), dim3(256), 0, stream>>>(xb, wqb, wkb, Qb, Kbf);
    attn_fwd<<<dim3(512), dim3(512), 0, stream>>>(Qb, Kbf, Vtb, pos, out);
}

// Round 24
// 75.193 us; speedup vs baseline: 1.1252x; 1.1252x over previous
//
#include <hip/hip_runtime.h>
#include <hip/hip_bf16.h>

typedef __bf16 bf16x8 __attribute__((ext_vector_type(8)));
typedef float f32x4 __attribute__((ext_vector_type(4)));
typedef float f32x16 __attribute__((ext_vector_type(16)));

__device__ inline unsigned short f2bf(float f) {
    __hip_bfloat16 h = __float2bfloat16(f);
    return __builtin_bit_cast(unsigned short, h);
}
// packed RNE f32->bf16 convert (HW op, single instruction): dst = {bf16(a), bf16(b)}
__device__ inline unsigned cvtpk(float a, float b) {
    unsigned r;
    asm("v_cvt_pk_bf16_f32 %0, %1, %2" : "=v"(r) : "v"(a), "v"(b));
    return r;
}
// truncation-pack: dst = {hi16(lo), hi16(hi)} via single v_perm_b32 (round-20 win).
__device__ inline unsigned pkhi(float lo, float hi) {
    return __builtin_amdgcn_perm(__builtin_bit_cast(unsigned, hi),
                                 __builtin_bit_cast(unsigned, lo), 0x07060302u);
}
__device__ inline float exp2_fast(float x) {
    float r;
    asm("v_exp_f32 %0, %1" : "=v"(r) : "v"(x));
    return r;
}

#define QSCALE 0.1803368801111244f  /* 0.125 * log2(e) */

// ------- fused projection + V-transpose: grid (64, 12) x 256 threads -----------------
// by 0..3:  Q = (x Wq^T) * QSCALE   (128x128 GEMM tile)
// by 4..7:  K = x Wk^T
// by 8..11: V transpose slice: x[b][n][hc+d] -> Vt[b*8+h][d][n'] for h = 2(by-8)+{0,1}.
//           n' = bit2<->bit3 permuted within 16-block (PV fragment contiguous 16B).
// Staging cvt uses HW v_cvt_pk_bf16_f32 (single instruction per bf16 pair).
__global__ __launch_bounds__(256) void gemm_qk(const float* __restrict__ x,
                                               const float* __restrict__ Wq,
                                               const float* __restrict__ Wk,
                                               unsigned short* __restrict__ Qb,
                                               unsigned short* __restrict__ Kb,
                                               unsigned short* __restrict__ Vt) {
    __shared__ __align__(16) unsigned short sA[128 * 40];
    __shared__ __align__(16) unsigned short sB[128 * 40];
    const int tid  = threadIdx.x;
    const int by = blockIdx.y;

    if (by >= 8) {  // ---- V transpose slice ----
        const int q = by - 8;
        const int nl = tid & 127, hh = tid >> 7;
        const int h = q * 2 + hh;
        const int g = blockIdx.x * 128 + nl;       // global row 0..8191
        const int b = g >> 11, n = g & 2047;
        const int np = (n & ~15) | (n & 3) | ((n & 4) << 1) | ((n & 8) >> 1);
        const size_t xrow = ((size_t)b * 2048 + n) * 512 + h * 64;
        const size_t vbase = ((size_t)(b * 8 + h) * 64) * 2048 + np;
#pragma unroll
        for (int d0 = 0; d0 < 64; d0 += 4) {
            float4 v = *reinterpret_cast<const float4*>(&x[xrow + d0]);
            Vt[vbase + (size_t)(d0 + 0) * 2048] = f2bf(v.x);
            Vt[vbase + (size_t)(d0 + 1) * 2048] = f2bf(v.y);
            Vt[vbase + (size_t)(d0 + 2) * 2048] = f2bf(v.z);
            Vt[vbase + (size_t)(d0 + 3) * 2048] = f2bf(v.w);
        }
        return;
    }

    const int lane = tid & 63;
    const int wave = tid >> 6;
    const int wr = wave >> 1, wc = wave & 1;
    const int bm = blockIdx.x * 128;
    const float* __restrict__ Bsrc = (by < 4) ? Wq : Wk;
    unsigned short* __restrict__ C = (by < 4) ? Qb : Kb;
    const int bn = (by & 3) * 128;
    const float scale = (by < 4) ? QSCALE : 1.0f;
    const int tr = tid >> 1, th = (tid & 1) * 16;
    const int rl = lane & 15;
    const int kq = (lane >> 4) * 8;

    f32x4 acc[4][4];
#pragma unroll
    for (int m = 0; m < 4; ++m)
#pragma unroll
        for (int n = 0; n < 4; ++n) acc[m][n] = (f32x4){0.f, 0.f, 0.f, 0.f};

    for (int k0 = 0; k0 < 512; k0 += 32) {
        const float* ap = &x[(size_t)(bm + tr) * 512 + k0 + th];
        const float* bp = &Bsrc[(size_t)(bn + tr) * 512 + k0 + th];
        float4 a0 = *reinterpret_cast<const float4*>(ap);
        float4 a1 = *reinterpret_cast<const float4*>(ap + 4);
        float4 a2 = *reinterpret_cast<const float4*>(ap + 8);
        float4 a3 = *reinterpret_cast<const float4*>(ap + 12);
        float4 b0 = *reinterpret_cast<const float4*>(bp);
        float4 b1 = *reinterpret_cast<const float4*>(bp + 4);
        float4 b2 = *reinterpret_cast<const float4*>(bp + 8);
        float4 b3 = *reinterpret_cast<const float4*>(bp + 12);
        uint4 pa0 = {cvtpk(a0.x, a0.y), cvtpk(a0.z, a0.w), cvtpk(a1.x, a1.y), cvtpk(a1.z, a1.w)};
        uint4 pa1 = {cvtpk(a2.x, a2.y), cvtpk(a2.z, a2.w), cvtpk(a3.x, a3.y), cvtpk(a3.z, a3.w)};
        uint4 pb0 = {cvtpk(b0.x, b0.y), cvtpk(b0.z, b0.w), cvtpk(b1.x, b1.y), cvtpk(b1.z, b1.w)};
        uint4 pb1 = {cvtpk(b2.x, b2.y), cvtpk(b2.z, b2.w), cvtpk(b3.x, b3.y), cvtpk(b3.z, b3.w)};
        __syncthreads();
        *reinterpret_cast<uint4*>(&sA[tr * 40 + th])     = pa0;
        *reinterpret_cast<uint4*>(&sA[tr * 40 + th + 8]) = pa1;
        *reinterpret_cast<uint4*>(&sB[tr * 40 + th])     = pb0;
        *reinterpret_cast<uint4*>(&sB[tr * 40 + th + 8]) = pb1;
        __syncthreads();

        bf16x8 af[4], bfv[4];
#pragma unroll
        for (int m = 0; m < 4; ++m)
            af[m] = __builtin_bit_cast(bf16x8,
                *reinterpret_cast<const uint4*>(&sA[(wr * 64 + m * 16 + rl) * 40 + kq]));
#pragma unroll
        for (int n = 0; n < 4; ++n)
            bfv[n] = __builtin_bit_cast(bf16x8,
                *reinterpret_cast<const uint4*>(&sB[(wc * 64 + n * 16 + rl) * 40 + kq]));
#pragma unroll
        for (int m = 0; m < 4; ++m)
#pragma unroll
            for (int n = 0; n < 4; ++n)
                acc[m][n] = __builtin_amdgcn_mfma_f32_16x16x32_bf16(af[m], bfv[n], acc[m][n], 0, 0, 0);
    }

    const int rq = (lane >> 4) * 4;
#pragma unroll
    for (int m = 0; m < 4; ++m) {
        int r = bm + wr * 64 + m * 16 + rq;
#pragma unroll
        for (int n = 0; n < 4; ++n) {
            int c = bn + wc * 64 + n * 16 + rl;
#pragma unroll
            for (int reg = 0; reg < 4; ++reg)
                C[(size_t)(r + reg) * 512 + c] = f2bf(acc[m][n][reg] * scale);
        }
    }
}

// ---------------- fused flash attention: 8 waves (4qh x 2jp), dbuf, 1 barrier/tile ---
// grid: 512 flat blocks, XCD bh-affinity (xcd=flat&7 owns bh {4xcd..4xcd+3}) -> per-XCD
// K/V working set 2MB, L2-resident. block: 512 = 8 waves; wave: qh=w&3, jp=w>>2.
// Fixed-reference softmax in log2 domain (log2e folded into Q-scale and slope).
// One-time sPos table (slopeL*pos, 8KB LDS) removes pos staging from the loop.
// P-pack via single v_perm_b32 truncation per pair (round-20 verified win).
// S^T: mfma(K,Q) -> D[row=j][col=q]: lane q=l31, j=(r&3)+8*(r>>2)+4*hi.
// PV: P-frag lane-local, j-map = 16ks + 4hi + (e&3) + 8*(e>>2); V pre-permuted so this
// fragment is one contiguous b128 read. LDS rows XOR-swizzled (byte ^= (row&7)<<4).
__global__ __launch_bounds__(512, 4) void attn_fwd(const unsigned short* __restrict__ Q,
                                                   const unsigned short* __restrict__ Kb,
                                                   const unsigned short* __restrict__ Vt,
                                                   const float* __restrict__ pos,
                                                   float* __restrict__ Out) {
    __shared__ __align__(16) unsigned char smem[42240];
    char* k0b = (char*)smem;                 // 8 KiB
    char* v0b = (char*)smem + 8192;          // 8 KiB
    char* k1b = (char*)smem + 16384;         // 8 KiB
    char* v1b = (char*)smem + 24576;         // 8 KiB
    float* sPosT = (float*)(smem + 32768);   // 2048 f32 slopeL*pos (8 KiB)
    float* sMl   = (float*)(smem + 40960);   // 256 f32 (epilogue l merge)

    const int tid  = threadIdx.x;
    const int lane = tid & 63;
    const int w    = tid >> 6;
    const int l31  = lane & 31;
    const int hi   = lane >> 5;
    const int qh   = w & 3;
    const int jp   = w >> 2;
    // XCD-affine decode (512 blocks, bijective: 512 % 8 == 0)
    const int flat = blockIdx.x;
    const int xcd  = flat & 7;
    const int idx  = flat >> 3;              // 0..63
    const int bh   = xcd * 4 + (idx >> 4);
    const int qt   = idx & 15;
    const int b = bh >> 3, h = bh & 7;
    const int q0 = qt * 128 + qh * 32;
    const size_t rowbase = (size_t)b * 2048;
    const int hc = h * 64;
    const float slopeL = ldexpf(1.4426950408889634f, -(h + 1));  // slope * log2(e)

    // Q B-fragments: lane supplies Q[q=l31][c = ks*16 + hi*8 + e] (Q pre-scaled)
    bf16x8 qf0, qf1, qf2, qf3;
    {
        const unsigned short* qp = &Q[(rowbase + q0 + l31) * 512 + hc + hi * 8];
        qf0 = __builtin_bit_cast(bf16x8, *reinterpret_cast<const uint4*>(qp));
        qf1 = __builtin_bit_cast(bf16x8, *reinterpret_cast<const uint4*>(qp + 16));
        qf2 = __builtin_bit_cast(bf16x8, *reinterpret_cast<const uint4*>(qp + 32));
        qf3 = __builtin_bit_cast(bf16x8, *reinterpret_cast<const uint4*>(qp + 48));
    }
    const float ui = slopeL * pos[rowbase + q0 + l31];

    // one-time slopeL*pos table (512 threads x 4 = 2048)
    {
        float4 v = reinterpret_cast<const float4*>(pos + rowbase)[tid];
        reinterpret_cast<f32x4*>(sPosT)[tid] =
            (f32x4){v.x * slopeL, v.y * slopeL, v.z * slopeL, v.w * slopeL};
    }

    float lloc = 0.f;
    f32x16 o0, o1;
#pragma unroll
    for (int r = 0; r < 16; ++r) { o0[r] = 0.f; o1[r] = 0.f; }

    // staging: 8 threads/row x 16 B; write slot XOR-swizzled -> conflict-free
    const int sr  = tid >> 3;                       // row 0..63
    const int sce = (tid & 7) * 8;                  // elem col (8 elems/thread)
    const int wbyte = sr * 128 + (((tid & 7) * 16) ^ ((sr & 7) << 4));
    const int kswz = (l31 & 7) << 4;                // compute-side swizzle key

    uint4 ck, cv;

    auto stage = [&](int j0v) {
        ck = *reinterpret_cast<const uint4*>(&Kb[(rowbase + j0v + sr) * 512 + hc + sce]);
        cv = *reinterpret_cast<const uint4*>(&Vt[((size_t)bh * 64 + sr) * 2048 + j0v + sce]);
    };
    auto writeb = [&](char* KB, char* VB) {
        *reinterpret_cast<uint4*>(KB + wbyte) = ck;
        *reinterpret_cast<uint4*>(VB + wbyte) = cv;
    };
    auto compute = [&](const char* KB, const char* VB, int j0) {
        const char* kr = KB + (32 * jp + l31) * 128;
        // ---- S chunk (32j x 32q) for this wave's (qh, jp) ----
        f32x16 s;
#pragma unroll
        for (int r = 0; r < 16; ++r) s[r] = 0.f;
        __builtin_amdgcn_s_setprio(1);
#pragma unroll
        for (int ks = 0; ks < 4; ++ks) {
            bf16x8 kf = __builtin_bit_cast(bf16x8,
                *reinterpret_cast<const uint4*>(kr + ((ks * 32 + hi * 16) ^ kswz)));
            bf16x8 qq = (ks == 0) ? qf0 : (ks == 1) ? qf1 : (ks == 2) ? qf2 : qf3;
            s = __builtin_amdgcn_mfma_f32_32x32x16_bf16(kf, qq, s, 0, 0, 0);
        }
        __builtin_amdgcn_s_setprio(0);

        // ---- bias + exp2 (fixed reference, log2 domain) ----
        float ls = 0.f;
#pragma unroll
        for (int t = 0; t < 4; ++t) {
            f32x4 u = *reinterpret_cast<const f32x4*>(&sPosT[j0 + 32 * jp + 8 * t + 4 * hi]);
#pragma unroll
            for (int r = 0; r < 4; ++r) {
                float p = exp2_fast(s[4 * t + r] - fabsf(u[r] - ui));
                s[4 * t + r] = p;
                ls += p;
            }
        }
        lloc += ls;

        // ---- lane-local P fragments (j = 16ks + 4hi + (e&3) + 8*(e>>2)) ----
        bf16x8 pf0 = __builtin_bit_cast(bf16x8, (uint4){
            pkhi(s[0], s[1]),  pkhi(s[2], s[3]),   pkhi(s[4], s[5]),   pkhi(s[6], s[7])});
        bf16x8 pf1 = __builtin_bit_cast(bf16x8, (uint4){
            pkhi(s[8], s[9]),  pkhi(s[10], s[11]), pkhi(s[12], s[13]), pkhi(s[14], s[15])});

        // ---- PV: O^T[d][q] += V-frag x P-frag; V pre-permuted -> single b128/frag ----
        const char* vr0 = VB + l31 * 128;
        const char* vr1 = VB + (32 + l31) * 128;
        __builtin_amdgcn_s_setprio(1);
#pragma unroll
        for (int ks = 0; ks < 2; ++ks) {
            const int cb = (64 * jp + ks * 32 + hi * 16) ^ kswz;  // permuted-stored
            bf16x8 v0 = __builtin_bit_cast(bf16x8, *reinterpret_cast<const uint4*>(vr0 + cb));
            bf16x8 v1 = __builtin_bit_cast(bf16x8, *reinterpret_cast<const uint4*>(vr1 + cb));
            bf16x8 pf = ks ? pf1 : pf0;
            o0 = __builtin_amdgcn_mfma_f32_32x32x16_bf16(v0, pf, o0, 0, 0, 0);
            o1 = __builtin_amdgcn_mfma_f32_32x32x16_bf16(v1, pf, o1, 0, 0, 0);
        }
        __builtin_amdgcn_s_setprio(0);
    };

    // prologue: tile 0 -> buf0; tile 1 -> regs
    stage(0);
    writeb(k0b, v0b);
    stage(64);
    __syncthreads();

    for (int t = 0; t < 32; t += 2) {
        // even iter: compute buf0, regs hold tile t+1 -> buf1
        writeb(k1b, v1b);
        if (t + 2 < 32) stage((t + 2) * 64);
        compute(k0b, v0b, t * 64);
        __syncthreads();
        // odd iter: compute buf1, regs hold tile t+2 -> buf0
        if (t + 2 < 32) {
            writeb(k0b, v0b);
            if (t + 3 < 32) stage((t + 3) * 64);
        }
        compute(k1b, v1b, (t + 1) * 64);
        __syncthreads();
    }

    // ---- epilogue: merge jp partials via LDS, normalize, direct 16B stores ----
    float lt = lloc + __shfl_xor(lloc, 32, 64);  // combine hi halves (same q)
    float* sM = (float*)smem;                    // aliases KV buffers (loop done)
    const int key = (lane & 7) << 2;
    if (jp == 1) {
        float* dst = sM + qh * 2048 + lane * 32;
#pragma unroll
        for (int i = 0; i < 4; ++i) {
            f32x4 t0 = {o0[4 * i], o0[4 * i + 1], o0[4 * i + 2], o0[4 * i + 3]};
            f32x4 t1 = {o1[4 * i], o1[4 * i + 1], o1[4 * i + 2], o1[4 * i + 3]};
            *reinterpret_cast<f32x4*>(dst + ((4 * i) ^ key))      = t0;
            *reinterpret_cast<f32x4*>(dst + ((16 + 4 * i) ^ key)) = t1;
        }
        sMl[qh * 64 + lane] = lt;
    }
    __syncthreads();
    if (jp == 0) {
        const float* src = sM + qh * 2048 + lane * 32;
#pragma unroll
        for (int i = 0; i < 4; ++i) {
            f32x4 t0 = *reinterpret_cast<const f32x4*>(src + ((4 * i) ^ key));
            f32x4 t1 = *reinterpret_cast<const f32x4*>(src + ((16 + 4 * i) ^ key));
#pragma unroll
            for (int r = 0; r < 4; ++r) { o0[4 * i + r] += t0[r]; o1[4 * i + r] += t1[r]; }
        }
        const float linv = 1.0f / (lt + sMl[qh * 64 + lane]);
        float* orow = &Out[(rowbase + q0 + l31) * 512 + hc];
#pragma unroll
        for (int t = 0; t < 4; ++t) {
            f32x4 a, c;
#pragma unroll
            for (int r = 0; r < 4; ++r) {
                a[r] = o0[4 * t + r] * linv;
                c[r] = o1[4 * t + r] * linv;
            }
            *reinterpret_cast<f32x4*>(orow + 8 * t + 4 * hi)      = a;
            *reinterpret_cast<f32x4*>(orow + 32 + 8 * t + 4 * hi) = c;
        }
    }
}

extern "C" void kernel_launch(void* const* d_in, const int* in_sizes, int n_in,
                              void* d_out, int out_size, void* d_ws, size_t ws_size,
                              hipStream_t stream) {
    const float* x   = (const float*)d_in[0];
    const float* pos = (const float*)d_in[1];
    const float* Wq  = (const float*)d_in[2];
    const float* Wk  = (const float*)d_in[3];
    float* out = (float*)d_out;

    // ws (bf16 elems): Q 4.19M | K 4.19M | Vt 4.19M  (~25MB)
    unsigned short* Qb  = (unsigned short*)d_ws;
    unsigned short* Kbf = Qb  + 4194304;
    unsigned short* Vtb = Kbf + 4194304;

    gemm_qk<<<dim3(64, 12), dim3(256), 0, stream>>>(x, Wq, Wk, Qb, Kbf, Vtb);
    attn_fwd<<<dim3(512), dim3(512), 0, stream>>>(Qb, Kbf, Vtb, pos, out);
}